// Round 1
// baseline (1046.816 us; speedup 1.0000x reference)
//
#include <hip/hip_runtime.h>

// Problem constants (from reference setup_inputs)
// B=64, T=64, F_in=2048, F_out=2048 -> GEMM M=4096, N=2048, K=2048
// h = x @ W^T + b ; tdBN over (B,T) per feature ; LIF scan over T.
// All computed in f64 so spike decisions match the numpy reference exactly.

#define TM 64
#define TN 64
#define TK 16

__global__ __launch_bounds__(256) void gemm_f64(
    const float* __restrict__ X,   // (4096, 2048) row-major
    const float* __restrict__ W,   // (2048, 2048) row-major (F_out, F_in)
    const float* __restrict__ bias,// (2048)
    double* __restrict__ H)        // (4096, 2048)
{
    constexpr int K = 2048, N = 2048;
    __shared__ __align__(16) double As[TK][TM];  // k-major
    __shared__ __align__(16) double Bs[TK][TN];

    const int tid = threadIdx.x;
    const int tx = tid & 15;        // output col group
    const int ty = tid >> 4;        // output row group
    const int bm = blockIdx.x * TM;
    const int bn = blockIdx.y * TN;

    // staging: each thread loads one float4 per matrix per tile
    const int lr = tid >> 2;              // row within tile (0..63)
    const int lc = (tid & 3) << 2;        // k offset (0,4,8,12)

    const float* xa = X + (size_t)(bm + lr) * K + lc;
    const float* wa = W + (size_t)(bn + lr) * K + lc;

    double acc[4][4] = {};
    const int ty4 = ty * 4;
    const int tx4 = tx * 4;

    for (int k0 = 0; k0 < K; k0 += TK) {
        float4 av = *reinterpret_cast<const float4*>(xa + k0);
        float4 bv = *reinterpret_cast<const float4*>(wa + k0);
        __syncthreads();   // previous tile's reads complete before overwrite
        As[lc + 0][lr] = (double)av.x;
        As[lc + 1][lr] = (double)av.y;
        As[lc + 2][lr] = (double)av.z;
        As[lc + 3][lr] = (double)av.w;
        Bs[lc + 0][lr] = (double)bv.x;
        Bs[lc + 1][lr] = (double)bv.y;
        Bs[lc + 2][lr] = (double)bv.z;
        Bs[lc + 3][lr] = (double)bv.w;
        __syncthreads();
        #pragma unroll
        for (int kk = 0; kk < TK; ++kk) {
            double a[4], b[4];
            *(double2*)&a[0] = *(const double2*)&As[kk][ty4];
            *(double2*)&a[2] = *(const double2*)&As[kk][ty4 + 2];
            *(double2*)&b[0] = *(const double2*)&Bs[kk][tx4];
            *(double2*)&b[2] = *(const double2*)&Bs[kk][tx4 + 2];
            #pragma unroll
            for (int i = 0; i < 4; ++i)
                #pragma unroll
                for (int j = 0; j < 4; ++j)
                    acc[i][j] = fma(a[i], b[j], acc[i][j]);
        }
    }

    #pragma unroll
    for (int i = 0; i < 4; ++i) {
        const size_t row = bm + ty4 + i;
        #pragma unroll
        for (int j = 0; j < 4; ++j) {
            const int col = bn + tx4 + j;
            H[row * N + col] = acc[i][j] + (double)bias[col];
        }
    }
}

// Stage 1: partial per-feature sums over chunks of 128 tokens
__global__ __launch_bounds__(256) void bn_partial(
    const double* __restrict__ H, double* __restrict__ psum, double* __restrict__ psq)
{
    constexpr int N = 2048, ROWS = 128;
    const int o  = blockIdx.x * 256 + threadIdx.x;
    const int t0 = blockIdx.y * ROWS;
    double s = 0.0, q = 0.0;
    for (int r = 0; r < ROWS; ++r) {
        double h = H[(size_t)(t0 + r) * N + o];
        s += h;
        q = fma(h, h, q);
    }
    psum[(size_t)blockIdx.y * N + o] = s;
    psq [(size_t)blockIdx.y * N + o] = q;
}

// Stage 2: finalize mean/var (biased, matches jnp.var ddof=0)
__global__ void bn_finalize(const double* __restrict__ psum, const double* __restrict__ psq,
                            double* __restrict__ meanv, double* __restrict__ varv)
{
    constexpr int N = 2048, CH = 32;
    const int o = blockIdx.x * blockDim.x + threadIdx.x;
    double s = 0.0, q = 0.0;
    for (int c = 0; c < CH; ++c) {
        s += psum[(size_t)c * N + o];
        q += psq [(size_t)c * N + o];
    }
    const double m = s / 4096.0;
    meanv[o] = m;
    varv[o]  = q / 4096.0 - m * m;
}

// Fused BN-normalize + LIF scan. One thread per (b, feature).
__global__ __launch_bounds__(256) void bn_lif(
    const double* __restrict__ H,
    const double* __restrict__ meanv, const double* __restrict__ varv,
    const float* __restrict__ gamma, const float* __restrict__ beta_bn,
    const float* __restrict__ mem_init,
    const float* __restrict__ lif_beta, const float* __restrict__ thr,
    float* __restrict__ out)
{
    constexpr int T = 64, F = 2048;
    const int gid = blockIdx.x * 256 + threadIdx.x;   // b*F + o
    const int o = gid & (F - 1);
    const int b = gid >> 11;

    const double m      = meanv[o];
    const double invstd = 1.0 / sqrt(varv[o] + 1e-5);   // ALPHA*VTH_BN = 1
    const double sc     = invstd * (double)gamma[o];
    const double sh     = (double)beta_bn[o];
    const double beta_c = fmin(fmax((double)lif_beta[0], 0.0), 1.0);
    const double th     = (double)thr[0];

    double mem = (double)mem_init[gid];
    const double* hp = H   + (size_t)b * T * F + o;
    float*        op = out + (size_t)b * T * F + o;

    for (int t = 0; t < T; ++t) {
        const double h  = hp[(size_t)t * F];
        const double xt = (h - m) * sc + sh;
        const double reset = (mem > th) ? th : 0.0;   // reset from PREVIOUS mem
        mem = fma(beta_c, mem, xt) - reset;
        op[(size_t)t * F] = (mem > th) ? 1.0f : 0.0f;
    }
}

extern "C" void kernel_launch(void* const* d_in, const int* in_sizes, int n_in,
                              void* d_out, int out_size, void* d_ws, size_t ws_size,
                              hipStream_t stream)
{
    const float* x        = (const float*)d_in[0];
    const float* mem_init = (const float*)d_in[1];
    const float* W        = (const float*)d_in[2];
    const float* b        = (const float*)d_in[3];
    const float* gamma    = (const float*)d_in[4];
    const float* beta_bn  = (const float*)d_in[5];
    const float* lif_beta = (const float*)d_in[6];
    const float* thr      = (const float*)d_in[7];
    float* out = (float*)d_out;

    char* ws = (char*)d_ws;
    double* H     = (double*)ws;                                  // 4096*2048*8 = 64 MiB
    double* psum  = (double*)(ws + (size_t)67108864);             // 32*2048*8
    double* psq   = (double*)(ws + (size_t)67108864 + 524288);
    double* meanv = (double*)(ws + (size_t)67108864 + 2 * 524288);
    double* varv  = meanv + 2048;

    gemm_f64   <<<dim3(64, 32), 256, 0, stream>>>(x, W, b, H);
    bn_partial <<<dim3(8, 32),  256, 0, stream>>>(H, psum, psq);
    bn_finalize<<<8,            256, 0, stream>>>(psum, psq, meanv, varv);
    bn_lif     <<<512,          256, 0, stream>>>(H, meanv, varv, gamma, beta_bn,
                                                  mem_init, lif_beta, thr, out);
}

// Round 4
// 791.444 us; speedup vs baseline: 1.3227x; 1.3227x over previous
//
#include <hip/hip_runtime.h>

// B=64, T=64, F_in=2048, F_out=2048 -> GEMM M=4096, N=2048, K=2048
// h = x @ W^T + b ; tdBN over (B,T) per feature ; LIF scan over T.
// Full f64 pipeline: round 1 passed with absmax == 0.0. MFMA-f64 path
// (rounds 2-3) failed un-localizably -> reverted to the verified VALU
// structure, now optimized per round-1 counters:
//   - 8x8 microtile: 1 B LDS per FLOP (was 2) -> LDS no longer the 50% cap
//   - stride-16 interleaved ownership: all ds_read_b64 conflict-free
//     (round 1: SQ_LDS_BANK_CONFLICT = 2.35e8 from 4-way B reads)
//   - 128x128 tile, BK=16, double-buffered 64 KB LDS, 2 blocks/CU,
//     one barrier per K-tile.

#define BMt 128
#define BNt 128
#define BKt 16

__global__ __launch_bounds__(256, 2) void gemm_f64_v2(
    const float* __restrict__ X,   // (4096, 2048) row-major
    const float* __restrict__ W,   // (2048, 2048) row-major (F_out, F_in)
    const float* __restrict__ bias,// (2048)
    double* __restrict__ H)        // (4096, 2048)
{
    constexpr int K = 2048, N = 2048, NT = K / BKt;
    __shared__ double As[2][BKt][BMt];   // k-major: As[buf][k][row]
    __shared__ double Bs[2][BKt][BNt];   // Bs[buf][k][col]

    const int tid = threadIdx.x;
    const int tx  = tid & 15;            // owns cols {tx + 16*j}
    const int ty  = tid >> 4;            // owns rows {ty + 16*i}
    const int bm  = blockIdx.x * BMt;
    const int bn  = blockIdx.y * BNt;

    // staging: thread t loads 8 f32 of row (t>>1), k-offset (t&1)*8
    const int arow = tid >> 1;           // 0..127
    const int acol = (tid & 1) * 8;      // 0 or 8
    const float* xa = X + (size_t)(bm + arow) * K + acol;
    const float* wa = W + (size_t)(bn + arow) * K + acol;

    double acc[8][8] = {};

    // prologue: stage k-tile 0
    {
        float4 a0 = *(const float4*)(xa);
        float4 a1 = *(const float4*)(xa + 4);
        float4 b0 = *(const float4*)(wa);
        float4 b1 = *(const float4*)(wa + 4);
        float av[8] = {a0.x, a0.y, a0.z, a0.w, a1.x, a1.y, a1.z, a1.w};
        float bv[8] = {b0.x, b0.y, b0.z, b0.w, b1.x, b1.y, b1.z, b1.w};
        #pragma unroll
        for (int q = 0; q < 8; ++q) {
            As[0][acol + q][arow] = (double)av[q];
            Bs[0][acol + q][arow] = (double)bv[q];
        }
    }
    __syncthreads();

    int cur = 0;
    for (int t = 0; t < NT; ++t) {
        const bool more = (t + 1) < NT;
        float4 a0, a1, b0, b1;
        if (more) {
            const int k0 = (t + 1) * BKt;
            a0 = *(const float4*)(xa + k0);
            a1 = *(const float4*)(xa + k0 + 4);
            b0 = *(const float4*)(wa + k0);
            b1 = *(const float4*)(wa + k0 + 4);
        }

        #pragma unroll 2
        for (int kk = 0; kk < BKt; ++kk) {
            double a[8], b[8];
            #pragma unroll
            for (int s = 0; s < 8; ++s) a[s] = As[cur][kk][ty + 16 * s];
            #pragma unroll
            for (int s = 0; s < 8; ++s) b[s] = Bs[cur][kk][tx + 16 * s];
            #pragma unroll
            for (int i = 0; i < 8; ++i)
                #pragma unroll
                for (int j = 0; j < 8; ++j)
                    acc[i][j] = fma(a[i], b[j], acc[i][j]);
        }

        if (more) {
            float av[8] = {a0.x, a0.y, a0.z, a0.w, a1.x, a1.y, a1.z, a1.w};
            float bv[8] = {b0.x, b0.y, b0.z, b0.w, b1.x, b1.y, b1.z, b1.w};
            #pragma unroll
            for (int q = 0; q < 8; ++q) {
                As[cur ^ 1][acol + q][arow] = (double)av[q];
                Bs[cur ^ 1][acol + q][arow] = (double)bv[q];
            }
            __syncthreads();   // writes to buf^1 visible; reads of buf done pre-write
        }
        cur ^= 1;
    }

    // epilogue: rows {bm+ty+16i}, cols {bn+tx+16j}
    #pragma unroll
    for (int j = 0; j < 8; ++j) {
        const int col = bn + tx + 16 * j;
        const double bj = (double)bias[col];
        #pragma unroll
        for (int i = 0; i < 8; ++i) {
            const int row = bm + ty + 16 * i;
            H[(size_t)row * N + col] = acc[i][j] + bj;
        }
    }
}

// Stage 1: partial per-feature sums over chunks of 128 tokens
__global__ __launch_bounds__(256) void bn_partial(
    const double* __restrict__ H, double* __restrict__ psum, double* __restrict__ psq)
{
    constexpr int N = 2048, ROWS = 128;
    const int o  = blockIdx.x * 256 + threadIdx.x;
    const int t0 = blockIdx.y * ROWS;
    double s = 0.0, q = 0.0;
    for (int r = 0; r < ROWS; ++r) {
        double h = H[(size_t)(t0 + r) * N + o];
        s += h;
        q = fma(h, h, q);
    }
    psum[(size_t)blockIdx.y * N + o] = s;
    psq [(size_t)blockIdx.y * N + o] = q;
}

// Stage 2: finalize mean/var (biased, matches jnp.var ddof=0)
__global__ void bn_finalize(const double* __restrict__ psum, const double* __restrict__ psq,
                            double* __restrict__ meanv, double* __restrict__ varv)
{
    constexpr int N = 2048, CH = 32;
    const int o = blockIdx.x * blockDim.x + threadIdx.x;
    double s = 0.0, q = 0.0;
    for (int c = 0; c < CH; ++c) {
        s += psum[(size_t)c * N + o];
        q += psq [(size_t)c * N + o];
    }
    const double m = s / 4096.0;
    meanv[o] = m;
    varv[o]  = q / 4096.0 - m * m;
}

// Fused BN-normalize + LIF scan. One thread per (b, feature).
__global__ __launch_bounds__(256) void bn_lif(
    const double* __restrict__ H,
    const double* __restrict__ meanv, const double* __restrict__ varv,
    const float* __restrict__ gamma, const float* __restrict__ beta_bn,
    const float* __restrict__ mem_init,
    const float* __restrict__ lif_beta, const float* __restrict__ thr,
    float* __restrict__ out)
{
    constexpr int T = 64, F = 2048;
    const int gid = blockIdx.x * 256 + threadIdx.x;   // b*F + o
    const int o = gid & (F - 1);
    const int b = gid >> 11;

    const double m      = meanv[o];
    const double invstd = 1.0 / sqrt(varv[o] + 1e-5);   // ALPHA*VTH_BN = 1
    const double sc     = invstd * (double)gamma[o];
    const double sh     = (double)beta_bn[o];
    const double beta_c = fmin(fmax((double)lif_beta[0], 0.0), 1.0);
    const double th     = (double)thr[0];

    double mem = (double)mem_init[gid];
    const double* hp = H   + (size_t)b * T * F + o;
    float*        op = out + (size_t)b * T * F + o;

    for (int t = 0; t < T; ++t) {
        const double h  = hp[(size_t)t * F];
        const double xt = (h - m) * sc + sh;
        const double reset = (mem > th) ? th : 0.0;   // reset from PREVIOUS mem
        mem = fma(beta_c, mem, xt) - reset;
        op[(size_t)t * F] = (mem > th) ? 1.0f : 0.0f;
    }
}

extern "C" void kernel_launch(void* const* d_in, const int* in_sizes, int n_in,
                              void* d_out, int out_size, void* d_ws, size_t ws_size,
                              hipStream_t stream)
{
    const float* x        = (const float*)d_in[0];
    const float* mem_init = (const float*)d_in[1];
    const float* W        = (const float*)d_in[2];
    const float* b        = (const float*)d_in[3];
    const float* gamma    = (const float*)d_in[4];
    const float* beta_bn  = (const float*)d_in[5];
    const float* lif_beta = (const float*)d_in[6];
    const float* thr      = (const float*)d_in[7];
    float* out = (float*)d_out;

    char* ws = (char*)d_ws;
    double* H     = (double*)ws;                                  // 4096*2048*8 = 64 MiB
    double* psum  = (double*)(ws + (size_t)67108864);             // 32*2048*8
    double* psq   = (double*)(ws + (size_t)67108864 + 524288);
    double* meanv = (double*)(ws + (size_t)67108864 + 2 * 524288);
    double* varv  = meanv + 2048;

    gemm_f64_v2<<<dim3(32, 16), 256, 0, stream>>>(x, W, b, H);
    bn_partial <<<dim3(8, 32),  256, 0, stream>>>(H, psum, psq);
    bn_finalize<<<8,            256, 0, stream>>>(psum, psq, meanv, varv);
    bn_lif     <<<512,          256, 0, stream>>>(H, meanv, varv, gamma, beta_bn,
                                                  mem_init, lif_beta, thr, out);
}